// Round 5
// baseline (970.442 us; speedup 1.0000x reference)
//
#include <hip/hip_runtime.h>
#include <hip/hip_bf16.h>
#include <math.h>

#define N_CB   8
#define M_EMB  1024
#define D_EMB  128
#define H_LAT  64
#define B_SZ   256
#define L_PER  (B_SZ * H_LAT)
#define TOTAL_X (B_SZ * N_CB * D_EMB * H_LAT)

/* d_out layout (floats): [z_q | loss | entropy | perplexity | indices] */
#define LOSS_OFF (TOTAL_X)
#define ENT_OFF  (TOTAL_X + 1)
#define PPL_OFF  (TOTAL_X + 2)
#define IDX_OFF  (TOTAL_X + 3)

/* ws layout (4-byte units) — max 180228 floats = 721KB (proven safe in r3) */
#define WS_ESQ_OFF   0
#define WS_IDX_OFF   8192
#define WS_CNT_OFF   139264
#define WS_LOSS_OFF  147456
#define WS_FCNT_OFF  147457
#define WS_FLAG_OFF  147460
#define FLAG_CAP     32768
#define TAU2         1.5e-3f

typedef __attribute__((ext_vector_type(8))) short short8;
typedef __attribute__((ext_vector_type(4))) float floatx4;

__device__ __forceinline__ unsigned int bf16rn(float f) {
    unsigned int u = __float_as_uint(f);
    return (u + 0x7FFFu + ((u >> 16) & 1u)) >> 16;   /* RNE, NaN-free inputs */
}

__global__ void init_ws(int* __restrict__ counts, float* __restrict__ lossacc,
                        int* __restrict__ flagcnt) {
    int t = blockIdx.x * 256 + threadIdx.x;
    if (t < N_CB * M_EMB) counts[t] = 0;
    if (t == 0) { *lossacc = 0.f; *flagcnt = 0; }
}

/* one wave per embedding row: e_sq[n,m] = sum_d e^2 */
__global__ void esq_kernel(const float* __restrict__ e, float* __restrict__ esq) {
    int wave = (blockIdx.x * blockDim.x + threadIdx.x) >> 6;
    int lane = threadIdx.x & 63;
    if (wave >= N_CB * M_EMB) return;
    float2 v = reinterpret_cast<const float2*>(e + (size_t)wave * D_EMB)[lane];
    float s = v.x * v.x + v.y * v.y;
    #pragma unroll
    for (int off = 32; off; off >>= 1) s += __shfl_down(s, off);
    if (lane == 0) esq[wave] = s;
}

/* MFMA distance-GEMM + argmin. grid = 8 n x 128 ltiles = 1024 blocks, 256 thr.
 * Block: 128 rows (2 b x 64 h) x all 1024 m, K=128. Wave (wr,wc): 64x64 tile.
 * LDS: As 32KB (bf16 swizzled) | Bs 32KB (bf16 swizzled, staged per-mc from f32).
 * dist key = fma(-2, cross, e_sq) with m embedded in low 10 mantissa bits;
 * running (min1,min2); near-ties (gap<TAU2) flagged for np-exact fixup. */
__launch_bounds__(256, 2)
__global__ void vq_mfma_kernel(const float* __restrict__ x,
                               const float* __restrict__ emb,
                               const float* __restrict__ esq,
                               int*  __restrict__ idx_ws,
                               int*  __restrict__ counts,
                               int*  __restrict__ flagcnt,
                               int*  __restrict__ flags,
                               float* __restrict__ out)
{
    __shared__ __align__(16) char smem[65536];   /* As 32KB | Bs 32KB */
    const int bid = blockIdx.x;
    const int n = bid >> 7, ltile = bid & 127;
    const int b0 = ltile * 2;
    const int t = threadIdx.x;
    const int l = t & 63, w = t >> 6;
    const int wr = w >> 1, wc = w & 1;

    /* ---- stage A: x tile 128 rows x 128 k -> bf16 swizzled ---- */
    {
        int r = t & 127, kh = t >> 7;
        int bb = r >> 6, h = r & 63;
        const float* gx = x + ((size_t)(b0 + bb) * N_CB + n) * (D_EMB * H_LAT) + h;
        int swz = (r & 15) << 4;
        char* arow = smem + r * 256;
        #pragma unroll 4
        for (int i = 0; i < 64; i += 4) {
            int k = kh * 64 + i;
            float f0 = gx[(size_t)(k + 0) * H_LAT];
            float f1 = gx[(size_t)(k + 1) * H_LAT];
            float f2 = gx[(size_t)(k + 2) * H_LAT];
            float f3 = gx[(size_t)(k + 3) * H_LAT];
            unsigned int p0 = bf16rn(f0) | (bf16rn(f1) << 16);
            unsigned int p1 = bf16rn(f2) | (bf16rn(f3) << 16);
            *reinterpret_cast<uint2*>(arow + ((2 * k) ^ swz)) = make_uint2(p0, p1);
        }
    }

    float m1[16], m2[16];
    #pragma unroll
    for (int i = 0; i < 16; i++) { m1[i] = INFINITY; m2[i] = INFINITY; }

    const float* ebase = emb + (size_t)n * M_EMB * D_EMB;
    const float* esq_n = esq + n * M_EMB;

    const int lx = l & 15;
    const int rbase = wr * 64 + lx;
    const int cbase = wc * 64 + lx;
    const int kb_lane = (l >> 4) * 16;     /* byte offset of lane's k-start */
    const int swzl = lx << 4;

    const int tk = t & 31;                 /* B-stage: float4 chunk along k */
    const int trow = t >> 5;               /* B-stage: row mod 8 */

    for (int mc = 0; mc < 8; ++mc) {
        __syncthreads();                   /* prior Bs consumers done / A staged */
        {   /* stage Bs: 128 m-rows x 128 k from f32 emb, convert + swizzle */
            #pragma unroll
            for (int rr = 0; rr < 16; ++rr) {
                int mrow = rr * 8 + trow;
                float4 v = *reinterpret_cast<const float4*>(
                    ebase + (size_t)(mc * 128 + mrow) * D_EMB + tk * 4);
                unsigned int p0 = bf16rn(v.x) | (bf16rn(v.y) << 16);
                unsigned int p1 = bf16rn(v.z) | (bf16rn(v.w) << 16);
                int swz = (mrow & 15) << 4;
                *reinterpret_cast<uint2*>(
                    smem + 32768 + mrow * 256 + ((tk * 8) ^ swz)) = make_uint2(p0, p1);
            }
        }
        __syncthreads();

        floatx4 acc[4][4];
        #pragma unroll
        for (int i = 0; i < 4; i++)
            #pragma unroll
            for (int j = 0; j < 4; j++)
                acc[i][j] = (floatx4){0.f, 0.f, 0.f, 0.f};

        #pragma unroll
        for (int kc = 0; kc < 4; ++kc) {
            const int kx = (kc * 64 + kb_lane) ^ swzl;
            short8 a[4], b[4];
            #pragma unroll
            for (int i = 0; i < 4; i++)
                a[i] = *reinterpret_cast<const short8*>(smem + (rbase + i * 16) * 256 + kx);
            #pragma unroll
            for (int j = 0; j < 4; j++)
                b[j] = *reinterpret_cast<const short8*>(smem + 32768 + (cbase + j * 16) * 256 + kx);
            #pragma unroll
            for (int i = 0; i < 4; i++)
                #pragma unroll
                for (int j = 0; j < 4; j++)
                    acc[i][j] = __builtin_amdgcn_mfma_f32_16x16x32_bf16(a[i], b[j], acc[i][j], 0, 0, 0);
        }

        /* epilogue: keys + running (m1,m2); index in low 10 mantissa bits */
        const int mb = mc * 128 + cbase;
        #pragma unroll
        for (int j = 0; j < 4; j++) {
            float eq = esq_n[mb + j * 16];
            unsigned int midx = (unsigned int)(mb + j * 16);
            #pragma unroll
            for (int i = 0; i < 4; i++) {
                #pragma unroll
                for (int r = 0; r < 4; r++) {
                    float dist = fmaf(-2.f, acc[i][j][r], eq);
                    float key = __uint_as_float((__float_as_uint(dist) & 0xFFFFFC00u) | midx);
                    int s = i * 4 + r;
                    m2[s] = fminf(m2[s], fmaxf(m1[s], key));
                    m1[s] = fminf(m1[s], key);
                }
            }
        }
    }

    /* reduce (m1,m2) across the 16 lanes of each l>>4 group */
    #pragma unroll
    for (int s = 0; s < 16; s++) {
        float v1 = m1[s], v2 = m2[s];
        #pragma unroll
        for (int off = 1; off < 16; off <<= 1) {
            float o1 = __shfl_xor(v1, off);
            float o2 = __shfl_xor(v2, off);
            v2 = fminf(fminf(v2, o2), fmaxf(v1, o1));
            v1 = fminf(v1, o1);
        }
        m1[s] = v1; m2[s] = v2;
    }

    __syncthreads();                   /* MFMA LDS reads done; reuse smem */
    float* red = reinterpret_cast<float*>(smem);   /* [128 rows][2 wc][2] */
    if (lx == 0) {
        #pragma unroll
        for (int i = 0; i < 4; i++)
            #pragma unroll
            for (int r = 0; r < 4; r++) {
                int row = wr * 64 + i * 16 + (l >> 4) * 4 + r;
                red[(row * 2 + wc) * 2 + 0] = m1[i * 4 + r];
                red[(row * 2 + wc) * 2 + 1] = m2[i * 4 + r];
            }
    }
    __syncthreads();
    if (wc == 0) {
        int row = wr * 64 + l;
        float a1 = red[(row * 2 + 0) * 2 + 0], a2 = red[(row * 2 + 0) * 2 + 1];
        float b1 = red[(row * 2 + 1) * 2 + 0], b2 = red[(row * 2 + 1) * 2 + 1];
        float v1 = fminf(a1, b1);
        float v2 = fminf(fminf(a2, b2), fmaxf(a1, b1));
        int i1 = (int)(__float_as_uint(v1) & 1023u);
        int b = b0 + wr, h = row & 63;
        int lidx = b * H_LAT + h;
        idx_ws[n * L_PER + lidx] = i1;
        atomicAdd(&counts[n * M_EMB + i1], 1);
        out[IDX_OFF + (b * N_CB + n) * H_LAT + h] = (float)i1;
        if (v2 - v1 < TAU2) {
            int slot = atomicAdd(flagcnt, 1);
            if (slot < FLAG_CAP) flags[slot] = (n << 14) | lidx;
        }
    }
}

/* np-fp32-semantics re-argmin for flagged rows. Pass 1: fast fp32-FMA screen;
 * pass 2: strict np emulation (4-stripe, separately-rounded) in window. */
__global__ void fixup_np_kernel(const float* __restrict__ x,
                                const float* __restrict__ emb,
                                const float* __restrict__ esq,
                                const int* __restrict__ flags,
                                const int* __restrict__ flagcnt,
                                int* __restrict__ idx_ws,
                                int* __restrict__ counts,
                                float* __restrict__ out)
{
    __shared__ float xrow[128];
    __shared__ float xsq_sh;
    __shared__ float redv[4];
    __shared__ int   redi[4];
    int cnt = *flagcnt;
    if (cnt > FLAG_CAP) cnt = FLAG_CAP;
    int t = threadIdx.x, lane = t & 63, w = t >> 6;

    for (int f = blockIdx.x; f < cnt; f += gridDim.x) {
        int key = flags[f];
        int n = key >> 14, lrow = key & (L_PER - 1);
        int b = lrow >> 6, h = lrow & 63;
        if (t < 128)
            xrow[t] = x[((size_t)b * N_CB + n) * (D_EMB * H_LAT) + (size_t)t * H_LAT + h];
        __syncthreads();
        if (t == 0) {
            double s = 0.0;
            for (int d = 0; d < 128; d++) { double v = (double)xrow[d]; s += v * v; }
            xsq_sh = (float)s;
        }
        __syncthreads();
        float xsq = xsq_sh;

        const float* eb  = emb + (size_t)n * M_EMB * D_EMB;
        const float* eqn = esq + n * M_EMB;

        /* pass 1: fast dists for my 4 candidates */
        float fd[4];
        float rmin = INFINITY;
        #pragma unroll
        for (int q = 0; q < 4; q++) {
            int m = q * 256 + t;
            const float* er = eb + (size_t)m * D_EMB;
            float acc = 0.f;
            #pragma unroll 8
            for (int d = 0; d < 128; d++) acc = fmaf(xrow[d], er[d], acc);
            fd[q] = eqn[m] + xsq - 2.f * acc;
            rmin = fminf(rmin, fd[q]);
        }
        #pragma unroll
        for (int off = 1; off < 64; off <<= 1) rmin = fminf(rmin, __shfl_xor(rmin, off));
        if (lane == 0) redv[w] = rmin;
        __syncthreads();
        rmin = fminf(fminf(redv[0], redv[1]), fminf(redv[2], redv[3]));
        __syncthreads();

        /* pass 2: strict np semantics within window */
        float bv = INFINITY; int bi = 0x7fffffff;
        for (int q = 0; q < 4; q++) {
            int m = q * 256 + t;
            if (fd[q] < rmin + 1e-3f) {
                const float* er = eb + (size_t)m * D_EMB;
                float a0 = 0.f, a1 = 0.f, a2 = 0.f, a3 = 0.f;
                #pragma unroll 8
                for (int i = 0; i < 128; i += 4) {
                    a0 = __fadd_rn(a0, __fmul_rn(xrow[i + 0], er[i + 0]));
                    a1 = __fadd_rn(a1, __fmul_rn(xrow[i + 1], er[i + 1]));
                    a2 = __fadd_rn(a2, __fmul_rn(xrow[i + 2], er[i + 2]));
                    a3 = __fadd_rn(a3, __fmul_rn(xrow[i + 3], er[i + 3]));
                }
                float cr   = __fadd_rn(__fadd_rn(a0, a1), __fadd_rn(a2, a3));
                float t1   = __fadd_rn(eqn[m], xsq);
                float dist = __fadd_rn(t1, __fmul_rn(-2.f, cr));
                if (dist < bv || (dist == bv && m < bi)) { bv = dist; bi = m; }
            }
        }
        #pragma unroll
        for (int off = 1; off < 64; off <<= 1) {
            float ov = __shfl_xor(bv, off);
            int   oi = __shfl_xor(bi, off);
            if (ov < bv || (ov == bv && oi < bi)) { bv = ov; bi = oi; }
        }
        if (lane == 0) { redv[w] = bv; redi[w] = bi; }
        __syncthreads();
        if (t == 0) {
            for (int w2 = 1; w2 < 4; w2++)
                if (redv[w2] < bv || (redv[w2] == bv && redi[w2] < bi)) {
                    bv = redv[w2]; bi = redi[w2];
                }
            int old = idx_ws[n * L_PER + lrow];
            if (old != bi) {
                idx_ws[n * L_PER + lrow] = bi;
                atomicSub(&counts[n * M_EMB + old], 1);
                atomicAdd(&counts[n * M_EMB + bi], 1);
                out[IDX_OFF + (b * N_CB + n) * H_LAT + h] = (float)bi;
            }
        }
        __syncthreads();
    }
}

/* z_q scatter + commitment loss. Block per (b,n): coalesced emb row gather
 * -> LDS (pitch 129, 2-way free) -> coalesced float4 writes. */
__global__ void scatter_loss_kernel(const float* __restrict__ x,
                                    const float* __restrict__ emb,
                                    const int* __restrict__ idx_ws,
                                    float* __restrict__ out,
                                    float* __restrict__ lossacc)
{
    __shared__ float q[64][129];
    __shared__ int   idxs[64];
    __shared__ float wsum[4];
    int bid = blockIdx.x;
    int n = bid & 7, b = bid >> 3;
    int t = threadIdx.x, lane = t & 63, w = t >> 6;

    if (t < 64) idxs[t] = idx_ws[n * L_PER + b * H_LAT + t];
    __syncthreads();
    for (int hh = w; hh < 64; hh += 4) {
        int m = idxs[hh];
        float2 v = *reinterpret_cast<const float2*>(
            emb + ((size_t)n * M_EMB + m) * D_EMB + lane * 2);
        q[hh][lane * 2]     = v.x;
        q[hh][lane * 2 + 1] = v.y;
    }
    __syncthreads();

    size_t base = ((size_t)b * N_CB + n) * (D_EMB * H_LAT);
    int h4 = (t & 15) * 4;
    float s = 0.f;
    #pragma unroll
    for (int p = 0; p < 8; p++) {      /* d = p*16 + (t>>4) in [0,128) */
        int d = p * 16 + (t >> 4);
        float4 xv = *reinterpret_cast<const float4*>(x + base + (size_t)d * H_LAT + h4);
        float4 qv = make_float4(q[h4][d], q[h4 + 1][d], q[h4 + 2][d], q[h4 + 3][d]);
        *reinterpret_cast<float4*>(out + base + (size_t)d * H_LAT + h4) = qv;
        float d0 = xv.x - qv.x, d1 = xv.y - qv.y, d2 = xv.z - qv.z, d3 = xv.w - qv.w;
        s += d0 * d0 + d1 * d1 + d2 * d2 + d3 * d3;
    }
    #pragma unroll
    for (int off = 32; off; off >>= 1) s += __shfl_down(s, off);
    if (lane == 0) wsum[w] = s;
    __syncthreads();
    if (t == 0) atomicAdd(lossacc, wsum[0] + wsum[1] + wsum[2] + wsum[3]);
}

/* entropy / perplexity + final loss. 1 block. */
__global__ void finish_kernel(const int* __restrict__ counts,
                              const float* __restrict__ lossacc,
                              float* __restrict__ out)
{
    __shared__ float red[16];
    int t = threadIdx.x;
    float entsum = 0.f, pplsum = 0.f;
    for (int n = 0; n < N_CB; n++) {
        float p = counts[n * M_EMB + t] * (1.f / L_PER);
        float s = p * logf(p + 1e-10f);
        #pragma unroll
        for (int off = 32; off; off >>= 1) s += __shfl_down(s, off);
        int lane = t & 63, w = t >> 6;
        if (lane == 0) red[w] = s;
        __syncthreads();
        if (t < 16) {
            float v = red[t];
            #pragma unroll
            for (int off = 8; off; off >>= 1) v += __shfl_down(v, off);
            if (t == 0) red[0] = v;
        }
        __syncthreads();
        float ent = -red[0];
        entsum += ent;
        pplsum += expf(ent);
        __syncthreads();
    }
    if (t == 0) {
        out[ENT_OFF]  = entsum * (1.f / N_CB);
        out[PPL_OFF]  = pplsum * (1.f / N_CB);
        out[LOSS_OFF] = 0.25f * (*lossacc) / (float)TOTAL_X;
    }
}

extern "C" void kernel_launch(void* const* d_in, const int* in_sizes, int n_in,
                              void* d_out, int out_size, void* d_ws, size_t ws_size,
                              hipStream_t stream)
{
    const float* x   = (const float*)d_in[0];
    const float* emb = (const float*)d_in[1];
    float* out = (float*)d_out;

    float* esq     = (float*)d_ws + WS_ESQ_OFF;
    int*   idx_ws  = (int*)d_ws + WS_IDX_OFF;
    int*   counts  = (int*)d_ws + WS_CNT_OFF;
    float* lossacc = (float*)d_ws + WS_LOSS_OFF;
    int*   flagcnt = (int*)d_ws + WS_FCNT_OFF;
    int*   flags   = (int*)d_ws + WS_FLAG_OFF;

    hipLaunchKernelGGL(init_ws, dim3(33), dim3(256), 0, stream, counts, lossacc, flagcnt);
    hipLaunchKernelGGL(esq_kernel, dim3(2048), dim3(256), 0, stream, emb, esq);
    hipLaunchKernelGGL(vq_mfma_kernel, dim3(1024), dim3(256), 0, stream,
                       x, emb, esq, idx_ws, counts, flagcnt, flags, out);
    hipLaunchKernelGGL(fixup_np_kernel, dim3(2048), dim3(256), 0, stream,
                       x, emb, esq, flags, flagcnt, idx_ws, counts, out);
    hipLaunchKernelGGL(scatter_loss_kernel, dim3(2048), dim3(256), 0, stream,
                       x, emb, idx_ws, out, lossacc);
    hipLaunchKernelGGL(finish_kernel, dim3(1), dim3(1024), 0, stream,
                       counts, lossacc, out);
}